// Round 2
// baseline (284.913 us; speedup 1.0000x reference)
//
#include <hip/hip_runtime.h>

// Problem: B=64, T=512, C_IN=128, C_OUT=16
// out[bt, i*C_OUT + j] = x[bt, i] * W[i, j] + b[i, j]
// x: [B*T, C_IN] f32 (16 MiB), W,b: [C_IN, C_OUT] f32 (8 KiB each),
// out: [B*T, C_IN*C_OUT] f32 (256 MiB). Pure HBM-write-bound broadcast FMA.
// Roofline: ~272 MiB / 6.3 TB/s ≈ 45 us.

constexpr int kB = 64;
constexpr int kT = 512;
constexpr int kCIn = 128;
constexpr int kCOut = 16;
constexpr int kRow = kCIn * kCOut;              // 2048 floats per bt row
constexpr int kRow4 = kRow / 4;                 // 512 float4 per row
constexpr int kN4 = kB * kT * kRow4;            // 16,777,216 float4 outputs

// grid*block = 2048*256 = 524288, a multiple of kRow4 (512) -> per-thread
// c4 = g & 511 is loop-invariant; W/b loads hoist out of the loop.

__global__ __launch_bounds__(256) void realemb_kernel(
    const float* __restrict__ x,
    const float4* __restrict__ W4,   // W viewed as [C_IN*C_OUT/4] float4
    const float4* __restrict__ b4,
    float4* __restrict__ out4)
{
    const int idx = blockIdx.x * blockDim.x + threadIdx.x;
    const int stride = gridDim.x * blockDim.x;     // 524288, multiple of 512

    const int c4 = idx & (kRow4 - 1);              // loop-invariant
    const int i = c4 >> 2;                         // input feature index
    const float4 w = W4[c4];
    const float4 bb = b4[c4];

    const int btStride = stride >> 9;              // bt advance per iteration
    int bt = idx >> 9;

    for (int g = idx; g < kN4; g += stride, bt += btStride) {
        float xv = x[bt * kCIn + i];
        float4 o;
        o.x = fmaf(xv, w.x, bb.x);
        o.y = fmaf(xv, w.y, bb.y);
        o.z = fmaf(xv, w.z, bb.z);
        o.w = fmaf(xv, w.w, bb.w);
        out4[g] = o;
    }
}

extern "C" void kernel_launch(void* const* d_in, const int* in_sizes, int n_in,
                              void* d_out, int out_size, void* d_ws, size_t ws_size,
                              hipStream_t stream) {
    const float* x = (const float*)d_in[0];
    const float4* W4 = (const float4*)d_in[1];
    const float4* b4 = (const float4*)d_in[2];
    float4* out4 = (float4*)d_out;

    const int block = 256;
    const int grid = 2048;  // ~8 blocks/CU on 256 CUs; grid-stride covers all
    realemb_kernel<<<grid, block, 0, stream>>>(x, W4, b4, out4);
}